// Round 1
// 2714.936 us; speedup vs baseline: 1.0740x; 1.0740x over previous
//
#include <hip/hip_runtime.h>
#include <stdint.h>

// Forbid mul+add contraction: distance arithmetic must match the numpy
// reference bit-for-bit (argmax / radius-compare are discontinuous).
// MLP math uses explicit fmaf() (exact FMA is fine; only ordering matters).
#pragma clang fp contract(off)

#define NPT   16384
#define BB    8
#define SS    1024
#define KSAMP 32
#define PTOT  (BB*SS*KSAMP)   // 262144
#define NGRP  (BB*SS)         // 8192
#define R2    0.04f
#define EPSBN 1e-5f
#define INV_M 3.814697265625e-06f   // 1/262144, exact power of two

// ws layout (floats)
#define OFF_S1 0
#define OFF_Q1 64
#define OFF_S2 128
#define OFF_Q2 192
#define OFF_S3 256    // 128
#define OFF_Q3 384    // 128
#define OFF_A1 512
#define OFF_C1 576
#define OFF_A2 640
#define OFF_C2 704
#define OFF_A3 768    // 128
#define OFF_C3 896    // 128
#define OFF_ZMAX 1024                  // 8192*128 = 1048576
#define OFF_FEAT (1024 + 1048576)      // 6*262144 = 1572864  (total ~10.5 MB)

// ---------------------------------------------------------------------------
// helpers
// ---------------------------------------------------------------------------
__device__ __forceinline__ float wave_sum(float v) {
#pragma unroll
  for (int off = 32; off; off >>= 1) v += __shfl_xor(v, off);
  return v;  // butterfly: all lanes hold identical total
}
__device__ __forceinline__ float half_max(float v) {
#pragma unroll
  for (int off = 16; off; off >>= 1) v = fmaxf(v, __shfl_xor(v, off));
  return v;  // max within each 32-lane half
}

// ---------------------------------------------------------------------------
// 1) Farthest point sampling: one block per batch, 512 thr x 32 pts/thread.
//    R3 DIAGNOSIS: VGPR_Count=84 (< the 128 needed for x/y/z/d residency)
//    proves the R2 asm-pin "fix" never landed — the compiler still re-fetches
//    96 floats/thread/iter from L1/L2 at 12B lane stride (~192 KB/CU/iter,
//    ~12 cache lines per reload instr) -> 2.29 us/iter, 2.6x above the VALU
//    floor. STRUCTURAL FIX: make residency not depend on the allocator.
//    (x,y) live in LDS as float2 (16384*8B = 128 KiB exactly — proven
//    per-workgroup size on gfx950); z + d stay in VGPRs (~100 regs, far
//    under the 256 cap at 2 waves/SIMD, so no spill pressure). Per-iter the
//    block reads 128 KB from LDS (~1024 cy @ 128 B/clk, conflict-free
//    stride-8 ds_read_b64, independent of the centroid load so it issues
//    under that latency) instead of thrashing L1->L2.
//    Argmax reduce uses a monotone u64 key (dist >= 0 so IEEE bits are
//    order-preserving; low word = ~idx gives lowest-index tie-break ==
//    jnp.argmax first-occurrence). Arithmetic order identical to the
//    passing version (bit-exact distances).
// ---------------------------------------------------------------------------
__global__ __launch_bounds__(512, 2)
void fps_kernel(const float* __restrict__ xyz, float* __restrict__ newxyz) {
  extern __shared__ float smem[];          // 128 KiB dynamic: float2 sxy[NPT]
  float2* sxy = (float2*)smem;
  const int b = blockIdx.x;
  const int t = threadIdx.x;
  const int lane = t & 63;
  const int w = t >> 6;                 // 8 waves
  const float* xb = xyz + (size_t)b * NPT * 3;

  float z[32], d[32];
#pragma unroll
  for (int j = 0; j < 32; ++j) {
    int p = j * 512 + t;
    float xx = xb[3 * p];
    float yy = xb[3 * p + 1];
    float zz = xb[3 * p + 2];
    sxy[p] = make_float2(xx, yy);
    z[j] = zz;
    d[j] = 1e10f;
    asm volatile("" : "+v"(z[j]));      // keep z materialized in a VGPR
  }

  __shared__ unsigned long long rk[2][8];  // double-buffered per-wave argmax keys

  int fi = 0;                            // current centroid index (uniform)
  if (t == 0) {
    float* o = newxyz + (size_t)b * SS * 3;   // idx[0] = 0
    o[0] = xb[0]; o[1] = xb[1]; o[2] = xb[2];
  }
  __syncthreads();                       // sxy visible to all waves

  for (int it = 1; it < SS; ++it) {
    // centroid: uniform index -> one cache line, broadcast to all lanes
    const float cx = xb[3 * fi], cy = xb[3 * fi + 1], cz = xb[3 * fi + 2];
    float bv = -1.0f; int bi = 0x7fffffff;
#pragma unroll
    for (int j = 0; j < 32; ++j) {
      int p = j * 512 + t;
      float2 xy = sxy[p];                         // LDS, loop-inv address
      float dx = xy.x - cx, dy = xy.y - cy, dz = z[j] - cz;
      float d2 = (dx * dx + dy * dy) + dz * dz;   // matches numpy order
      float dm = fminf(d[j], d2);
      d[j] = dm;
      if (dm > bv) { bv = dm; bi = p; }           // strict > keeps lowest idx
    }
    // monotone key: hi = float bits (dist >= 0), lo = ~idx (tie -> low idx)
    unsigned long long k =
        ((unsigned long long)__float_as_uint(bv) << 32) | (unsigned)(~bi);
#pragma unroll
    for (int off = 32; off; off >>= 1) {          // wave argmax butterfly
      unsigned long long o = __shfl_xor(k, off);
      if (o > k) k = o;
    }
    const int buf = it & 1;
    if (lane == 0) rk[buf][w] = k;
    __syncthreads();
    // single barrier is safe: next iteration writes the OTHER buffer, and
    // the barrier of iteration it+1 orders those writes after these reads.
    unsigned long long km = rk[buf][0];
#pragma unroll
    for (int ww = 1; ww < 8; ++ww) {
      unsigned long long o = rk[buf][ww];
      if (o > km) km = o;
    }
    fi = (int)(~(unsigned)(km & 0xffffffffull));
    fi = __builtin_amdgcn_readfirstlane(fi);      // tell compiler: uniform
    if (t == 0) {
      float* o = newxyz + ((size_t)b * SS + it) * 3;
      o[0] = xb[3 * fi]; o[1] = xb[3 * fi + 1]; o[2] = xb[3 * fi + 2];
    }
  }
}

// ---------------------------------------------------------------------------
// 2) Ball query + gather (fused): one wave per centroid, ascending-index scan
//    with ballot == ref's sort+slice. feat is channel-major [6][PTOT].
// ---------------------------------------------------------------------------
__global__ __launch_bounds__(256, 2)
void ballq_kernel(const float* __restrict__ xyz, const float* __restrict__ pts,
                  const float* __restrict__ newxyz, float* __restrict__ feat) {
  const int lane = threadIdx.x & 63;
  const int c = blockIdx.x * 4 + (threadIdx.x >> 6);  // 0..8191
  const int b = c >> 10;
  const float* xb = xyz + (size_t)b * NPT * 3;
  const float* pb = pts + (size_t)b * NPT * 3;
  const float cx = newxyz[3 * c], cy = newxyz[3 * c + 1], cz = newxyz[3 * c + 2];
  const int base = c * KSAMP;
  const uint64_t ltm = (1ull << lane) - 1ull;

  int cnt = 0, firstp = 0;
  bool haveFirst = false;
  for (int p0 = 0; p0 < NPT && cnt < KSAMP; p0 += 64) {
    int p = p0 + lane;
    float px = xb[3 * p], py = xb[3 * p + 1], pz = xb[3 * p + 2];
    float dx = cx - px, dy = cy - py, dz = cz - pz;
    float sqr = (dx * dx + dy * dy) + dz * dz;
    bool in = (sqr <= R2);                          // !(sqr > r^2)
    uint64_t m = __ballot(in);
    if (!haveFirst && m) { firstp = p0 + (__ffsll((unsigned long long)m) - 1); haveFirst = true; }
    int rank = (int)__popcll(m & ltm);
    int slot = cnt + rank;
    if (in && slot < KSAMP) {
      int idx = base + slot;
      feat[0 * PTOT + idx] = px - cx;
      feat[1 * PTOT + idx] = py - cy;
      feat[2 * PTOT + idx] = pz - cz;
      feat[3 * PTOT + idx] = pb[3 * p];
      feat[4 * PTOT + idx] = pb[3 * p + 1];
      feat[5 * PTOT + idx] = pb[3 * p + 2];
    }
    cnt += (int)__popcll(m);
  }
  if (cnt < KSAMP) {  // pad with first in-ball point (center itself qualifies)
    int slot = cnt + lane;
    if (slot < KSAMP) {
      int idx = base + slot;
      float px = xb[3 * firstp], py = xb[3 * firstp + 1], pz = xb[3 * firstp + 2];
      feat[0 * PTOT + idx] = px - cx;
      feat[1 * PTOT + idx] = py - cy;
      feat[2 * PTOT + idx] = pz - cz;
      feat[3 * PTOT + idx] = pb[3 * firstp];
      feat[4 * PTOT + idx] = pb[3 * firstp + 1];
      feat[5 * PTOT + idx] = pb[3 * firstp + 2];
    }
  }
}

// ---------------------------------------------------------------------------
// 3) stats of layer-1 pre-activations. Per-thread s[64],q[64] (cheap here:
//    only 6 FMA per channel). Block-reduce -> global atomics.
// ---------------------------------------------------------------------------
__global__ __launch_bounds__(256, 2)
void mlp1s_kernel(const float* __restrict__ feat, const float* __restrict__ w0,
                  const float* __restrict__ b0, float* __restrict__ stats) {
  float s[64], q[64];
#pragma unroll
  for (int o = 0; o < 64; ++o) { s[o] = 0.0f; q[o] = 0.0f; }
  int gid = blockIdx.x * 256 + threadIdx.x;
  for (int p = gid; p < PTOT; p += 256 * 256) {
    float f[6];
#pragma unroll
    for (int ch = 0; ch < 6; ++ch) f[ch] = feat[ch * PTOT + p];
#pragma unroll
    for (int o = 0; o < 64; ++o) {
      float z = b0[o];
#pragma unroll
      for (int i = 0; i < 6; ++i) z = fmaf(w0[o * 6 + i], f[i], z);
      s[o] += z; q[o] = fmaf(z, z, q[o]);
    }
  }
  const int lane = threadIdx.x & 63;
#pragma unroll
  for (int o = 0; o < 64; ++o) { s[o] = wave_sum(s[o]); q[o] = wave_sum(q[o]); }
  __shared__ float ls[128];
  if (threadIdx.x < 128) ls[threadIdx.x] = 0.0f;
  __syncthreads();
  if (lane == 0) {
#pragma unroll
    for (int o = 0; o < 64; ++o) { atomicAdd(&ls[o], s[o]); atomicAdd(&ls[64 + o], q[o]); }
  }
  __syncthreads();
  if (threadIdx.x < 64) atomicAdd(&stats[OFF_S1 + threadIdx.x], ls[threadIdx.x]);
  else if (threadIdx.x < 128) atomicAdd(&stats[OFF_Q1 + threadIdx.x - 64], ls[threadIdx.x]);
}

// ---------------------------------------------------------------------------
// BN fold: a = g/sqrt(var+eps), c = be - a*mu   (h = relu(a*z + c))
// ---------------------------------------------------------------------------
__global__ void fin_kernel(const float* __restrict__ g, const float* __restrict__ be,
                           const float* __restrict__ s, const float* __restrict__ q,
                           float* __restrict__ A, float* __restrict__ C, int Cn) {
  int o = blockIdx.x * blockDim.x + threadIdx.x;
  if (o >= Cn) return;
  float mu = s[o] * INV_M;
  float var = q[o] * INV_M - mu * mu;
  float a = g[o] / sqrtf(var + EPSBN);
  A[o] = a;
  C[o] = be[o] - a * mu;
}

// ---------------------------------------------------------------------------
// 4) stats of layer-2 pre-activations. h1 built explicitly (unrolled o),
//    then rolled-o loop: scalar z2 accumulators + wave-butterfly stats into
//    designated-lane registers.
// ---------------------------------------------------------------------------
__global__ __launch_bounds__(256, 2)
void mlp2s_kernel(const float* __restrict__ feat,
                  const float* __restrict__ w0, const float* __restrict__ b0,
                  const float* __restrict__ w1, const float* __restrict__ b1,
                  const float* __restrict__ par, float* __restrict__ stats) {
  const float* a1 = par + OFF_A1;
  const float* c1 = par + OFF_C1;
  const int lane = threadIdx.x & 63;
  float sp = 0.0f, qp = 0.0f;          // this lane's channel (== lane)
  int gid = blockIdx.x * 256 + threadIdx.x;
  for (int p = gid; p < PTOT; p += 512 * 256) {
    float f[6];
#pragma unroll
    for (int ch = 0; ch < 6; ++ch) f[ch] = feat[ch * PTOT + p];
    float h1[64];
#pragma unroll
    for (int o = 0; o < 64; ++o) {
      float z = b0[o];
#pragma unroll
      for (int i = 0; i < 6; ++i) z = fmaf(w0[o * 6 + i], f[i], z);
      h1[o] = fmaxf(fmaf(a1[o], z, c1[o]), 0.0f);
    }
    for (int o = 0; o < 64; o += 2) {   // rolled: scalar temps only
      float z0 = b1[o], z1 = b1[o + 1];
#pragma unroll
      for (int i = 0; i < 64; ++i) {
        z0 = fmaf(w1[o * 64 + i], h1[i], z0);
        z1 = fmaf(w1[(o + 1) * 64 + i], h1[i], z1);
      }
      float s0 = wave_sum(z0), q0 = wave_sum(z0 * z0);
      float s1 = wave_sum(z1), q1 = wave_sum(z1 * z1);
      if (lane == o)     { sp += s0; qp += q0; }
      if (lane == o + 1) { sp += s1; qp += q1; }
    }
  }
  atomicAdd(&stats[OFF_S2 + lane], sp);
  atomicAdd(&stats[OFF_Q2 + lane], qp);
}

// ---------------------------------------------------------------------------
// 5) layer-3 fused: recompute h1 (per-i, no array), accumulate h2[64]
//    (i-rolled, o-unrolled), then rolled-o layer-3 with butterfly stats +
//    half-wave max. Writes zmax[g][o] (raw pre-BN max; valid because a3>0
//    makes relu(a*z+c) monotone).
// ---------------------------------------------------------------------------
__global__ __launch_bounds__(256, 2)
void mlp3f_kernel(const float* __restrict__ feat,
                  const float* __restrict__ w0, const float* __restrict__ b0,
                  const float* __restrict__ w1, const float* __restrict__ b1,
                  const float* __restrict__ w2, const float* __restrict__ b2,
                  const float* __restrict__ par, float* __restrict__ stats,
                  float* __restrict__ zmax) {
  const float* a1 = par + OFF_A1;
  const float* c1 = par + OFF_C1;
  const float* a2 = par + OFF_A2;
  const float* c2 = par + OFF_C2;
  const int lane = threadIdx.x & 63;
  float sp0 = 0.0f, qp0 = 0.0f;        // channel lane
  float sp1 = 0.0f, qp1 = 0.0f;        // channel 64+lane
  int gid = blockIdx.x * 256 + threadIdx.x;
  for (int p = gid; p < PTOT; p += 512 * 256) {
    float f[6];
#pragma unroll
    for (int ch = 0; ch < 6; ++ch) f[ch] = feat[ch * PTOT + p];
    float h2[64];
#pragma unroll
    for (int o = 0; o < 64; ++o) h2[o] = b1[o];
    for (int i = 0; i < 64; ++i) {      // rolled; h1[i] recomputed (8 instr)
      float z = b0[i];
#pragma unroll
      for (int ch = 0; ch < 6; ++ch) z = fmaf(w0[i * 6 + ch], f[ch], z);
      float h1i = fmaxf(fmaf(a1[i], z, c1[i]), 0.0f);
#pragma unroll
      for (int o = 0; o < 64; ++o) h2[o] = fmaf(w1[o * 64 + i], h1i, h2[o]);
    }
#pragma unroll
    for (int o = 0; o < 64; ++o) h2[o] = fmaxf(fmaf(a2[o], h2[o], c2[o]), 0.0f);

    const int g = p >> 5;               // this lane's group
    for (int o = 0; o < 128; o += 2) {  // rolled: scalar temps
      float z0 = b2[o], z1 = b2[o + 1];
#pragma unroll
      for (int i = 0; i < 64; ++i) {
        z0 = fmaf(w2[o * 64 + i], h2[i], z0);
        z1 = fmaf(w2[(o + 1) * 64 + i], h2[i], z1);
      }
      float s0 = wave_sum(z0), q0 = wave_sum(z0 * z0);
      float s1 = wave_sum(z1), q1 = wave_sum(z1 * z1);
      if (lane == (o & 63))       { if (o < 64) { sp0 += s0; qp0 += q0; } else { sp1 += s0; qp1 += q0; } }
      if (lane == ((o + 1) & 63)) { if (o < 64) { sp0 += s1; qp0 += q1; } else { sp1 += s1; qp1 += q1; } }
      float m0 = half_max(z0), m1 = half_max(z1);
      if ((lane & 31) == (o & 31))       zmax[g * 128 + o]     = m0;
      if ((lane & 31) == ((o + 1) & 31)) zmax[g * 128 + o + 1] = m1;
    }
  }
  atomicAdd(&stats[OFF_S3 + lane], sp0);
  atomicAdd(&stats[OFF_Q3 + lane], qp0);
  atomicAdd(&stats[OFF_S3 + 64 + lane], sp1);
  atomicAdd(&stats[OFF_Q3 + 64 + lane], qp1);
}

// ---------------------------------------------------------------------------
// 6) epilogue: out2[g][c] = relu(a3[c]*zmax[g][c] + c3[c])
// ---------------------------------------------------------------------------
__global__ __launch_bounds__(256, 4)
void final_out_kernel(const float* __restrict__ zmax, const float* __restrict__ par,
                      float* __restrict__ out2) {
  const float* a3 = par + OFF_A3;
  const float* c3 = par + OFF_C3;
  int idx = blockIdx.x * 256 + threadIdx.x;   // g*128 + c
  int c = idx & 127;
  out2[idx] = fmaxf(fmaf(a3[c], zmax[idx], c3[c]), 0.0f);
}

// ---------------------------------------------------------------------------
extern "C" void kernel_launch(void* const* d_in, const int* in_sizes, int n_in,
                              void* d_out, int out_size, void* d_ws, size_t ws_size,
                              hipStream_t stream) {
  const float* xyz = (const float*)d_in[0];
  const float* pts = (const float*)d_in[1];
  const float* w0  = (const float*)d_in[2];
  const float* b0  = (const float*)d_in[3];
  const float* g0  = (const float*)d_in[4];
  const float* be0 = (const float*)d_in[5];
  const float* w1  = (const float*)d_in[6];
  const float* b1  = (const float*)d_in[7];
  const float* g1  = (const float*)d_in[8];
  const float* be1 = (const float*)d_in[9];
  const float* w2  = (const float*)d_in[10];
  const float* b2  = (const float*)d_in[11];
  const float* g2  = (const float*)d_in[12];
  const float* be2 = (const float*)d_in[13];

  float* out  = (float*)d_out;
  float* nxz  = out;                 // (B,S,3)
  float* out2 = out + BB * SS * 3;   // (B,S,128)

  float* ws    = (float*)d_ws;
  float* stats = ws;                 // 512 floats, zeroed every call
  float* par   = ws;                 // params addressed via OFF_* macros
  float* zmax  = ws + OFF_ZMAX;
  float* feat  = ws + OFF_FEAT;

  hipMemsetAsync(stats, 0, 512 * sizeof(float), stream);

  // 128 KiB dynamic LDS: float2 (x,y) per point; z+d stay in VGPRs
  fps_kernel<<<BB, 512, NPT * sizeof(float2), stream>>>(xyz, nxz);
  ballq_kernel<<<2048, 256, 0, stream>>>(xyz, pts, nxz, feat);

  mlp1s_kernel<<<256, 256, 0, stream>>>(feat, w0, b0, stats);
  fin_kernel<<<1, 64, 0, stream>>>(g0, be0, stats + OFF_S1, stats + OFF_Q1,
                                   par + OFF_A1, par + OFF_C1, 64);
  mlp2s_kernel<<<512, 256, 0, stream>>>(feat, w0, b0, w1, b1, par, stats);
  fin_kernel<<<1, 64, 0, stream>>>(g1, be1, stats + OFF_S2, stats + OFF_Q2,
                                   par + OFF_A2, par + OFF_C2, 64);
  mlp3f_kernel<<<512, 256, 0, stream>>>(feat, w0, b0, w1, b1, w2, b2, par, stats, zmax);
  fin_kernel<<<1, 128, 0, stream>>>(g2, be2, stats + OFF_S3, stats + OFF_Q3,
                                    par + OFF_A3, par + OFF_C3, 128);
  final_out_kernel<<<4096, 256, 0, stream>>>(zmax, par, out2);
}